// Round 9
// baseline (256.732 us; speedup 1.0000x reference)
//
#include <hip/hip_runtime.h>

typedef short bf16x8 __attribute__((ext_vector_type(8)));
typedef float f32x4 __attribute__((ext_vector_type(4)));
typedef unsigned short u16;

#define B_   16
#define S_   1024
#define F_   512
#define H_   8
#define DK_  64

// Inputs/outputs are FLOAT32 (established rounds 3/7). cvt_all converts x +
// weights to bf16 once; all hot loops are pure bf16. Intermediates bf16.

__device__ __forceinline__ u16 f2bf(float f) {
    union { float f; unsigned int u; } v; v.f = f;
    return (u16)((v.u + 0x7FFFu + ((v.u >> 16) & 1u)) >> 16);
}
__device__ __forceinline__ float bf2f(u16 h) {
    union { unsigned int u; float f; } v; v.u = ((unsigned int)h) << 16;
    return v.f;
}
__device__ __forceinline__ bf16x8 cvt8(float4 a, float4 b) {
    union { u16 u[8]; bf16x8 v; } r;
    r.u[0] = f2bf(a.x); r.u[1] = f2bf(a.y); r.u[2] = f2bf(a.z); r.u[3] = f2bf(a.w);
    r.u[4] = f2bf(b.x); r.u[5] = f2bf(b.y); r.u[6] = f2bf(b.z); r.u[7] = f2bf(b.w);
    return r.v;
}

// async global->LDS, 16 B per lane. LDS dest = wave-uniform base + lane*16.
__device__ __forceinline__ void gl_lds16(const u16* g, u16* l) {
    __builtin_amdgcn_global_load_lds(
        (const __attribute__((address_space(1))) unsigned int*)g,
        (__attribute__((address_space(3))) unsigned int*)l,
        16, 0, 0);
}

// ---------------------------------------------------------------------------
// One-shot f32 -> bf16 conversion of x and all weights/biases.
// unit = 8 elems. grid 4609 x 256 (exact).
// ---------------------------------------------------------------------------
__global__ __launch_bounds__(256) void cvt_all(
    const float* __restrict__ x,
    const float* __restrict__ wq, const float* __restrict__ wk,
    const float* __restrict__ wv, const float* __restrict__ wo,
    const float* __restrict__ bq, const float* __restrict__ bk,
    const float* __restrict__ bv, const float* __restrict__ bo,
    u16* __restrict__ Xbf, u16* __restrict__ Wbase)
{
    const size_t u = (size_t)blockIdx.x * 256 + threadIdx.x;
    const float* src; u16* dst;
    if (u < 1048576)      { src = x  + u * 8;               dst = Xbf + u * 8; }
    else if (u < 1081344) { src = wq + (u - 1048576) * 8;   dst = Wbase + (u - 1048576) * 8; }
    else if (u < 1114112) { src = wk + (u - 1081344) * 8;   dst = Wbase +  262144 + (u - 1081344) * 8; }
    else if (u < 1146880) { src = wv + (u - 1114112) * 8;   dst = Wbase +  524288 + (u - 1114112) * 8; }
    else if (u < 1179648) { src = wo + (u - 1146880) * 8;   dst = Wbase +  786432 + (u - 1146880) * 8; }
    else if (u < 1179712) { src = bq + (u - 1179648) * 8;   dst = Wbase + 1048576 + (u - 1179648) * 8; }
    else if (u < 1179776) { src = bk + (u - 1179712) * 8;   dst = Wbase + 1049088 + (u - 1179712) * 8; }
    else if (u < 1179840) { src = bv + (u - 1179776) * 8;   dst = Wbase + 1049600 + (u - 1179776) * 8; }
    else                  { src = bo + (u - 1179840) * 8;   dst = Wbase + 1050112 + (u - 1179840) * 8; }
    *(bf16x8*)dst = cvt8(*(const float4*)src, *(const float4*)(src + 4));
}

// ---------------------------------------------------------------------------
// Fused K+V projection GEMM (m97 pattern): B = [WK;WV] (1024 rows), bias =
// [bk;bv]. C[m,n] = sum_k A[m,k]*B[n,k] + bias[n]. n<512 -> K [bh][s][d];
// n>=512 -> V^T [bh][d][s]. grid (128, 8), block 256.
// ---------------------------------------------------------------------------
__global__ __launch_bounds__(256) void gemm_kv(
    const u16* __restrict__ A, const u16* __restrict__ Bm,
    const u16* __restrict__ bias, u16* __restrict__ Kout, u16* __restrict__ Vout)
{
    __shared__ __align__(16) u16 AsL[4096];  // [128][32] unpadded (gl_lds layout)
    __shared__ __align__(16) u16 BsL[4096];

    const int t    = threadIdx.x;
    const int wave = t >> 6, lane = t & 63;
    const int l15  = lane & 15, quad = lane >> 4;
    const int wr   = (wave & 1) * 64, wc = (wave >> 1) * 64;
    const int m0   = blockIdx.x * 128, n0 = blockIdx.y * 128;
    const int sr   = t >> 2, scol = (t & 3) * 8;

    f32x4 acc[4][4];
#pragma unroll
    for (int i = 0; i < 4; i++)
#pragma unroll
        for (int j = 0; j < 4; j++) acc[i][j] = {0.f, 0.f, 0.f, 0.f};

    const u16* Ab = A  + (size_t)(m0 + sr) * 512 + scol;
    const u16* Bb = Bm + (size_t)(n0 + sr) * 512 + scol;
    u16* la = &AsL[t * 8];
    u16* lb = &BsL[t * 8];

    for (int k0 = 0; k0 < 512; k0 += 32) {
        gl_lds16(Ab + k0,         la);
        gl_lds16(Ab + 32768 + k0, la + 2048);
        gl_lds16(Bb + k0,         lb);
        gl_lds16(Bb + 32768 + k0, lb + 2048);
        __syncthreads();
        bf16x8 af[4], bfv[4];
#pragma unroll
        for (int i = 0; i < 4; i++) af[i]  = *(const bf16x8*)&AsL[(wr + i * 16 + l15) * 32 + quad * 8];
#pragma unroll
        for (int j = 0; j < 4; j++) bfv[j] = *(const bf16x8*)&BsL[(wc + j * 16 + l15) * 32 + quad * 8];
#pragma unroll
        for (int i = 0; i < 4; i++)
#pragma unroll
            for (int j = 0; j < 4; j++)
                acc[i][j] = __builtin_amdgcn_mfma_f32_16x16x32_bf16(af[i], bfv[j], acc[i][j], 0, 0, 0);
        __syncthreads();
    }

#pragma unroll
    for (int j = 0; j < 4; j++) {
        const int n  = n0 + wc + j * 16 + l15;
        const float bv = bf2f(bias[n]);
        const int isv = n >> 9;                 // 0 = K, 1 = V (uniform per 16-lane group)
        const int nv  = n & 511, hh = nv >> 6, d = nv & 63;
#pragma unroll
        for (int i = 0; i < 4; i++) {
#pragma unroll
            for (int r = 0; r < 4; r++) {
                const int m = m0 + wr + i * 16 + quad * 4 + r;
                const int b = m >> 10, s = m & 1023;
                const float val = acc[i][j][r] + bv;
                if (isv) Vout[((size_t)(b * 8 + hh) * 64 + d) * 1024 + s] = f2bf(val);
                else     Kout[((size_t)(b * 8 + hh) * 1024 + s) * 64 + d] = f2bf(val);
            }
        }
    }
}

// ---------------------------------------------------------------------------
// Output projection GEMM (m97 pattern): C[m,n] f32 = Z*WO^T + bo.
// grid (128, 4), block 256.
// ---------------------------------------------------------------------------
__global__ __launch_bounds__(256) void gemm_out(
    const u16* __restrict__ A, const u16* __restrict__ Bm,
    const u16* __restrict__ bias, float* __restrict__ out)
{
    __shared__ __align__(16) u16 AsL[4096];
    __shared__ __align__(16) u16 BsL[4096];

    const int t    = threadIdx.x;
    const int wave = t >> 6, lane = t & 63;
    const int l15  = lane & 15, quad = lane >> 4;
    const int wr   = (wave & 1) * 64, wc = (wave >> 1) * 64;
    const int m0   = blockIdx.x * 128, n0 = blockIdx.y * 128;
    const int sr   = t >> 2, scol = (t & 3) * 8;

    f32x4 acc[4][4];
#pragma unroll
    for (int i = 0; i < 4; i++)
#pragma unroll
        for (int j = 0; j < 4; j++) acc[i][j] = {0.f, 0.f, 0.f, 0.f};

    const u16* Ab = A  + (size_t)(m0 + sr) * 512 + scol;
    const u16* Bb = Bm + (size_t)(n0 + sr) * 512 + scol;
    u16* la = &AsL[t * 8];
    u16* lb = &BsL[t * 8];

    for (int k0 = 0; k0 < 512; k0 += 32) {
        gl_lds16(Ab + k0,         la);
        gl_lds16(Ab + 32768 + k0, la + 2048);
        gl_lds16(Bb + k0,         lb);
        gl_lds16(Bb + 32768 + k0, lb + 2048);
        __syncthreads();
        bf16x8 af[4], bfv[4];
#pragma unroll
        for (int i = 0; i < 4; i++) af[i]  = *(const bf16x8*)&AsL[(wr + i * 16 + l15) * 32 + quad * 8];
#pragma unroll
        for (int j = 0; j < 4; j++) bfv[j] = *(const bf16x8*)&BsL[(wc + j * 16 + l15) * 32 + quad * 8];
#pragma unroll
        for (int i = 0; i < 4; i++)
#pragma unroll
            for (int j = 0; j < 4; j++)
                acc[i][j] = __builtin_amdgcn_mfma_f32_16x16x32_bf16(af[i], bfv[j], acc[i][j], 0, 0, 0);
        __syncthreads();
    }

#pragma unroll
    for (int j = 0; j < 4; j++) {
        const int n  = n0 + wc + j * 16 + l15;
        const float bv = bf2f(bias[n]);
#pragma unroll
        for (int i = 0; i < 4; i++) {
#pragma unroll
            for (int r = 0; r < 4; r++) {
                const int m = m0 + wr + i * 16 + quad * 4 + r;
                out[(size_t)m * 512 + n] = acc[i][j][r] + bv;
            }
        }
    }
}

// ---------------------------------------------------------------------------
// Flash attention, fused Q projection, 128 q-rows/block (32/wave), no-max
// online softmax, mask-aware tile skipping. Flattened 1D grid, batch-fastest
// for load balance. K: [bh][s][d]; Vt: [bh][d][s]; Z: [b,s,h*64+d] bf16.
// LDS 36 KB -> 4 blocks/CU. grid 1024, block 256.
// ---------------------------------------------------------------------------
__global__ __launch_bounds__(256) void attn(
    const u16* __restrict__ Xbf, const u16* __restrict__ Wqbf,
    const u16* __restrict__ bqbf,
    const u16* __restrict__ Kg, const u16* __restrict__ Vt,
    const int* __restrict__ xlen, u16* __restrict__ Z)
{
    // u16 map: phase1 As[128][32]@0 (4096), Bs[64][32]@4096 (2048) |
    //          phase2 Ks[64][72]@0 (4608), Vs[64][72]@4608 |
    //          PQ per-wave [32][72] @9216 (4x2304). total 18432 u16 = 36 KB
    __shared__ __align__(16) u16 smem[18432];

    const int t    = threadIdx.x;
    const int wave = t >> 6, lane = t & 63;
    const int l15  = lane & 15, quad = lane >> 4;
    const int blk  = blockIdx.x;
    const int b    = blk & 15, h = (blk >> 4) & 7, bx = blk >> 7;
    const int bh   = b * 8 + h;
    const int q0   = bx * 128;
    const int xm1  = xlen[b] - 1;
    const int PQ   = 9216 + wave * 2304;     // this wave's [32][72] (Q then P)

    // ---- phase 1: Q[128][64] = Xbf[b, q0..+127, :] * Wq[h]^T + bias, x1/8 ----
    // wave w computes its OWN q-rows w*32..+31 (all 64 cols) -> private handoff
    f32x4 qa[2][4];
#pragma unroll
    for (int m = 0; m < 2; m++)
#pragma unroll
        for (int j = 0; j < 4; j++) qa[m][j] = {0.f, 0.f, 0.f, 0.f};

    const u16* Xg = Xbf  + (size_t)(b * 1024 + q0 + (t >> 2)) * 512 + (t & 3) * 8;
    const u16* Wg = Wqbf + (size_t)(h * 64 + (t >> 2)) * 512 + (t & 3) * 8;

    for (int k0 = 0; k0 < 512; k0 += 32) {
        gl_lds16(Xg + k0,             &smem[t * 8]);          // rows q0..+63
        gl_lds16(Xg + 64 * 512 + k0,  &smem[2048 + t * 8]);   // rows q0+64..+127
        gl_lds16(Wg + k0,             &smem[4096 + t * 8]);   // Wq 64 rows
        __syncthreads();
        bf16x8 af[2], bfv[4];
#pragma unroll
        for (int m = 0; m < 2; m++)
            af[m] = *(const bf16x8*)&smem[(wave * 32 + m * 16 + l15) * 32 + quad * 8];
#pragma unroll
        for (int j = 0; j < 4; j++)
            bfv[j] = *(const bf16x8*)&smem[4096 + (j * 16 + l15) * 32 + quad * 8];
#pragma unroll
        for (int m = 0; m < 2; m++)
#pragma unroll
            for (int j = 0; j < 4; j++)
                qa[m][j] = __builtin_amdgcn_mfma_f32_16x16x32_bf16(af[m], bfv[j], qa[m][j], 0, 0, 0);
        __syncthreads();
    }
    // handoff: C-layout acc -> wave-private [32][72] slot (row = m*16+quad*4+r)
#pragma unroll
    for (int j = 0; j < 4; j++) {
        const float bv = bf2f(bqbf[h * 64 + j * 16 + l15]);
#pragma unroll
        for (int m = 0; m < 2; m++)
#pragma unroll
            for (int r = 0; r < 4; r++)
                smem[PQ + (m * 16 + quad * 4 + r) * 72 + j * 16 + l15] =
                    f2bf((qa[m][j][r] + bv) * 0.125f);
    }
    // A-frag reads from own slot (in-wave DS order; no barrier needed)
    bf16x8 aq[2][2];
#pragma unroll
    for (int m = 0; m < 2; m++)
#pragma unroll
        for (int kk = 0; kk < 2; kk++)
            aq[m][kk] = *(const bf16x8*)&smem[PQ + (m * 16 + l15) * 72 + kk * 32 + quad * 8];

    // ---- phase 2: 64-key tiles; skip tiles fully past xm1 ----
    const size_t baseKV = (size_t)bh * (S_ * DK_);
    const bool domask = (xm1 >= 1);
    const int  Slim   = domask ? xm1 : S_;

    f32x4 o[2][4];
#pragma unroll
    for (int m = 0; m < 2; m++)
#pragma unroll
        for (int j = 0; j < 4; j++) o[m][j] = {0.f, 0.f, 0.f, 0.f};
    float li[2][4] = {{0.f,0.f,0.f,0.f},{0.f,0.f,0.f,0.f}};

    const int srow = t >> 3, scl = (t & 7) * 8;   // 32 rows x 64 cols per chunk

    for (int t0 = 0; t0 < Slim; t0 += 64) {
        *(uint4*)&smem[srow * 72 + scl]               = *(const uint4*)&Kg[baseKV + (size_t)(t0 + srow) * 64 + scl];
        *(uint4*)&smem[(srow + 32) * 72 + scl]        = *(const uint4*)&Kg[baseKV + (size_t)(t0 + srow + 32) * 64 + scl];
        *(uint4*)&smem[4608 + srow * 72 + scl]        = *(const uint4*)&Vt[baseKV + (size_t)srow * 1024 + t0 + scl];
        *(uint4*)&smem[4608 + (srow + 32) * 72 + scl] = *(const uint4*)&Vt[baseKV + (size_t)(srow + 32) * 1024 + t0 + scl];
        __syncthreads();

        f32x4 sc[2][4];
#pragma unroll
        for (int nh = 0; nh < 4; nh++) {
            bf16x8 bk0 = *(const bf16x8*)&smem[(nh * 16 + l15) * 72 + quad * 8];
            bf16x8 bk1 = *(const bf16x8*)&smem[(nh * 16 + l15) * 72 + 32 + quad * 8];
#pragma unroll
            for (int m = 0; m < 2; m++) {
                f32x4 s = {0.f, 0.f, 0.f, 0.f};
                s = __builtin_amdgcn_mfma_f32_16x16x32_bf16(aq[m][0], bk0, s, 0, 0, 0);
                s = __builtin_amdgcn_mfma_f32_16x16x32_bf16(aq[m][1], bk1, s, 0, 0, 0);
                sc[m][nh] = s;
            }
        }
        if (domask && (t0 + 64 > xm1)) {     // only the last partial tile masks
#pragma unroll
            for (int nh = 0; nh < 4; nh++) {
                const float madd = ((t0 + nh * 16 + l15) >= xm1) ? -999999.0f : 0.0f;
#pragma unroll
                for (int m = 0; m < 2; m++)
#pragma unroll
                    for (int r = 0; r < 4; r++) sc[m][nh][r] += madd;
            }
        }
#pragma unroll
        for (int m = 0; m < 2; m++)
#pragma unroll
            for (int r = 0; r < 4; r++) {
                float e0 = __expf(sc[m][0][r]), e1 = __expf(sc[m][1][r]);
                float e2 = __expf(sc[m][2][r]), e3 = __expf(sc[m][3][r]);
                li[m][r] += (e0 + e1) + (e2 + e3);
                const int pr = PQ + (m * 16 + quad * 4 + r) * 72;
                smem[pr + l15]      = f2bf(e0);
                smem[pr + 16 + l15] = f2bf(e1);
                smem[pr + 32 + l15] = f2bf(e2);
                smem[pr + 48 + l15] = f2bf(e3);
            }
        // no barrier: PQ slot is wave-private, DS pipe in-order per wave
        bf16x8 ap[2][2];
#pragma unroll
        for (int m = 0; m < 2; m++)
#pragma unroll
            for (int kk = 0; kk < 2; kk++)
                ap[m][kk] = *(const bf16x8*)&smem[PQ + (m * 16 + l15) * 72 + kk * 32 + quad * 8];
#pragma unroll
        for (int j = 0; j < 4; j++) {
#pragma unroll
            for (int kk = 0; kk < 2; kk++) {
                bf16x8 bv8 = *(const bf16x8*)&smem[4608 + (j * 16 + l15) * 72 + kk * 32 + quad * 8];
#pragma unroll
                for (int m = 0; m < 2; m++)
                    o[m][j] = __builtin_amdgcn_mfma_f32_16x16x32_bf16(ap[m][kk], bv8, o[m][j], 0, 0, 0);
            }
        }
        __syncthreads();   // protect Ks/Vs for next tile
    }

    // final li reduce (16 lanes share each q-row) + epilogue
#pragma unroll
    for (int m = 0; m < 2; m++) {
        float linv[4];
#pragma unroll
        for (int r = 0; r < 4; r++) {
            float rs = li[m][r];
#pragma unroll
            for (int msk = 1; msk < 16; msk <<= 1) rs += __shfl_xor(rs, msk);
            linv[r] = 1.0f / rs;
        }
#pragma unroll
        for (int j = 0; j < 4; j++) {
#pragma unroll
            for (int r = 0; r < 4; r++) {
                const int s = q0 + wave * 32 + m * 16 + quad * 4 + r;
                Z[((size_t)(b * 1024 + s)) * 512 + h * 64 + j * 16 + l15] =
                    f2bf(o[m][j][r] * linv[r]);
            }
        }
    }
}

// ---------------------------------------------------------------------------
extern "C" void kernel_launch(void* const* d_in, const int* in_sizes, int n_in,
                              void* d_out, int out_size, void* d_ws, size_t ws_size,
                              hipStream_t stream)
{
    (void)in_sizes; (void)n_in; (void)out_size; (void)ws_size;

    const float* x    = (const float*)d_in[0];
    const int*   xlen = (const int*)d_in[1];
    const float* WQw  = (const float*)d_in[2];
    const float* WQb  = (const float*)d_in[3];
    const float* WKw  = (const float*)d_in[4];
    const float* WKb  = (const float*)d_in[5];
    const float* WVw  = (const float*)d_in[6];
    const float* WVb  = (const float*)d_in[7];
    const float* WOw  = (const float*)d_in[8];
    const float* WOb  = (const float*)d_in[9];

    const size_t NQ = (size_t)B_ * H_ * S_ * DK_;  // 8388608
    // ws: Kb | Zb | bf16 weights+biases (~35.7 MB, proven round 8)
    u16* Kb    = (u16*)d_ws;
    u16* Zb    = Kb + NQ;
    u16* Wbase = Zb + NQ;
    u16* WQbf  = Wbase;
    u16* WKVbf = Wbase + 262144;          // WK then WV, contiguous [1024][512]
    u16* WObf  = Wbase + 786432;
    u16* bqbf  = Wbase + 1048576;
    u16* bkvbf = Wbase + 1049088;         // bk then bv, contiguous [1024]
    u16* bobf  = Wbase + 1050112;
    // d_out (f32, 33.55 MB) temporarily holds Xbf @0 and V^T @NQ; both dead
    // before gemm_out overwrites d_out
    u16* Xbf = (u16*)d_out;
    u16* Vb  = Xbf + NQ;

    dim3 blk(256);
    cvt_all<<<dim3(4609), blk, 0, stream>>>(x, WQw, WKw, WVw, WOw,
                                            WQb, WKb, WVb, WOb, Xbf, Wbase);

    gemm_kv<<<dim3(128, 8), blk, 0, stream>>>(Xbf, WKVbf, bkvbf, Kb, Vb);

    attn<<<dim3(1024), blk, 0, stream>>>(Xbf, WQbf, bqbf, Kb, Vb, xlen, Zb);

    gemm_out<<<dim3(128, 4), blk, 0, stream>>>(Zb, WObf, bobf, (float*)d_out);
}